// Round 1
// 574.719 us; speedup vs baseline: 1.0074x; 1.0074x over previous
//
#include <hip/hip_runtime.h>
#include <stdint.h>

#define JAX_PARTITIONABLE 1

// ---------- helpers ----------
__device__ __forceinline__ float tanh_f(float x) {
  float e = __expf(2.0f * x);
  return 1.0f - 2.0f / (e + 1.0f);
}
__device__ __forceinline__ float sigm(float x) {
  return 1.0f / (1.0f + __expf(-x));
}

// ---------- Threefry-2x32 (JAX-compatible) ----------
__device__ __forceinline__ void tf2x32(unsigned k0, unsigned k1, unsigned x0, unsigned x1,
                                       unsigned &o0, unsigned &o1) {
  unsigned ks0 = k0, ks1 = k1, ks2 = k0 ^ k1 ^ 0x1BD11BDAu;
  x0 += ks0; x1 += ks1;
#define RR(r) { x0 += x1; x1 = (x1 << r) | (x1 >> (32 - r)); x1 ^= x0; }
  RR(13) RR(15) RR(26) RR(6)  x0 += ks1; x1 += ks2 + 1u;
  RR(17) RR(29) RR(16) RR(24) x0 += ks2; x1 += ks0 + 2u;
  RR(13) RR(15) RR(26) RR(6)  x0 += ks0; x1 += ks1 + 3u;
  RR(17) RR(29) RR(16) RR(24) x0 += ks1; x1 += ks2 + 4u;
  RR(13) RR(15) RR(26) RR(6)  x0 += ks2; x1 += ks0 + 5u;
#undef RR
  o0 = x0; o1 = x1;
}

// keep iff top bit of bits == 0 (keep prob 0.5); returns mask/keep scale
__device__ __forceinline__ float drop_scale(unsigned k0, unsigned k1, unsigned flat) {
#if JAX_PARTITIONABLE
  unsigned o0, o1; tf2x32(k0, k1, 0u, flat, o0, o1);
  unsigned bits = o0 ^ o1;
#else
  unsigned o0, o1, bits;
  if (flat < 8192u) { tf2x32(k0, k1, flat, flat + 8192u, o0, o1); bits = o0; }
  else             { tf2x32(k0, k1, flat - 8192u, flat, o0, o1); bits = o1; }
#endif
  return (bits >> 31) ? 0.0f : 2.0f;
}
__device__ __forceinline__ void get_drop_keys(unsigned &a0, unsigned &a1,
                                              unsigned &b0, unsigned &b1) {
#if JAX_PARTITIONABLE
  tf2x32(0u, 42u, 0u, 0u, a0, a1);
  tf2x32(0u, 42u, 0u, 1u, b0, b1);
#else
  unsigned p0, q0, p1, q1;
  tf2x32(0u, 42u, 0u, 2u, p0, q0);
  tf2x32(0u, 42u, 1u, 3u, p1, q1);
  a0 = p0; a1 = p1; b0 = q0; b1 = q1;
#endif
}

// =================================================================
// Kernel P0: all prep — zero/bias init + transposes into [k][64] layouts
// =================================================================
__global__ __launch_bounds__(256) void kP0(
    const float* prenet_in, const float* context_vec, const float* attn_hidden,
    const float* rnn1_hidden, const float* rnn2_hidden,
    const float* ri_b, const float* l1_b_ih, const float* l1_b_hh,
    const float* l2_b_ih, const float* l2_b_hh,
    const float* gru_b_ih, const float* gru_b_hh,
    float* ctx_f, float* xT, float* g1T, float* g2T, float* h1pT, float* h2pT,
    float* pinT, float* cvT, float* ahT0, float* grz, float* gin, float* ghn) {
  const int gid = blockIdx.x * 256 + threadIdx.x;
  const int GS = 128 * 256;
  for (int i = gid; i < 131072; i += GS) { int n = i >> 6; g1T[i] = l1_b_ih[n] + l1_b_hh[n]; }
  for (int i = gid; i < 131072; i += GS) { int n = i >> 6; g2T[i] = l2_b_ih[n] + l2_b_hh[n]; }
  for (int i = gid; i < 32768; i += GS) ctx_f[i] = 0.0f;
  for (int i = gid; i < 32768; i += GS) xT[i] = ri_b[i >> 6];
  for (int i = gid; i < 32768; i += GS) { int k = i >> 6, b = i & 63; h1pT[i] = rnn1_hidden[b * 512 + k]; }
  for (int i = gid; i < 32768; i += GS) { int k = i >> 6, b = i & 63; h2pT[i] = rnn2_hidden[b * 512 + k]; }
  for (int i = gid; i < 32768; i += GS) { int k = i >> 6, b = i & 63; cvT[i] = context_vec[b * 512 + k]; }
  for (int i = gid; i < 8192; i += GS)  { int k = i >> 6, b = i & 63; ahT0[i] = attn_hidden[b * 128 + k]; }
  for (int i = gid; i < 5120; i += GS)  { int k = i >> 6, b = i & 63; pinT[i] = prenet_in[b * 80 + k]; }
  for (int i = gid; i < 16384; i += GS) { int n = i >> 6; grz[i] = gru_b_ih[n] + gru_b_hh[n]; }
  for (int i = gid; i < 8192; i += GS)  { int n = i >> 6; gin[i] = gru_b_ih[256 + n]; }
  for (int i = gid; i < 8192; i += GS)  { int n = i >> 6; ghn[i] = gru_b_hh[256 + n]; }
}

// =================================================================
// Kernel P1: PreNet fc1 + relu + dropout1.  wave = 4 output rows, lane = batch
// =================================================================
__global__ __launch_bounds__(256) void kP1(const float* pinT, const float* fc1_w,
                                           const float* fc1_b, float* phT) {
  int wv = blockIdx.x * 4 + (threadIdx.x >> 6);  // 64 waves
  int lane = threadIdx.x & 63;
  int n0 = wv * 4;
  unsigned d1k0, d1k1, d2k0, d2k1;
  get_drop_keys(d1k0, d1k1, d2k0, d2k1);
  float acc[4] = {fc1_b[n0], fc1_b[n0 + 1], fc1_b[n0 + 2], fc1_b[n0 + 3]};
  #pragma unroll 4
  for (int k = 0; k < 80; k += 2) {
    float x0 = pinT[k * 64 + lane];
    float x1 = pinT[(k + 1) * 64 + lane];
    #pragma unroll
    for (int j = 0; j < 4; j++) {
      float2 w = *(const float2*)(fc1_w + (n0 + j) * 80 + k);
      acc[j] += x0 * w.x + x1 * w.y;
    }
  }
  #pragma unroll
  for (int j = 0; j < 4; j++) {
    float v = fmaxf(acc[j], 0.0f) * drop_scale(d1k0, d1k1, (unsigned)(lane * 256 + n0 + j));
    phT[(n0 + j) * 64 + lane] = v;
  }
}

// =================================================================
// Kernel P2: PreNet fc2 + relu + dropout2
// =================================================================
__global__ __launch_bounds__(256) void kP2(const float* phT, const float* fc2_w,
                                           const float* fc2_b, float* poT) {
  int wv = blockIdx.x * 4 + (threadIdx.x >> 6);  // 64 waves
  int lane = threadIdx.x & 63;
  int n0 = wv * 4;
  unsigned d1k0, d1k1, d2k0, d2k1;
  get_drop_keys(d1k0, d1k1, d2k0, d2k1);
  float acc[4] = {fc2_b[n0], fc2_b[n0 + 1], fc2_b[n0 + 2], fc2_b[n0 + 3]};
  #pragma unroll 4
  for (int k = 0; k < 256; k += 2) {
    float x0 = phT[k * 64 + lane];
    float x1 = phT[(k + 1) * 64 + lane];
    #pragma unroll
    for (int j = 0; j < 4; j++) {
      float2 w = *(const float2*)(fc2_w + (n0 + j) * 256 + k);
      acc[j] += x0 * w.x + x1 * w.y;
    }
  }
  #pragma unroll
  for (int j = 0; j < 4; j++) {
    float v = fmaxf(acc[j], 0.0f) * drop_scale(d2k0, d2k1, (unsigned)(lane * 256 + n0 + j));
    poT[(n0 + j) * 64 + lane] = v;
  }
}

// =================================================================
// Kernel P3: GRU gi (384 rows, K=768 split in 2 halves) + gh (384 rows, K=128)
// atomicAdd into bias-initialized grz / gin / ghn
// =================================================================
__global__ __launch_bounds__(256) void kP3(const float* cvT, const float* poT, const float* ahT0,
                                           const float* gru_w_ih, const float* gru_w_hh,
                                           float* grz, float* gin, float* ghn) {
  int wv = blockIdx.x * 4 + (threadIdx.x >> 6);  // 576 waves
  int lane = threadIdx.x & 63;
  if (wv < 384) {
    int rp = wv % 192, kh = wv / 192;
    int n0 = rp * 2;
    const float* w0 = gru_w_ih + (size_t)n0 * 768;
    const float* w1 = w0 + 768;
    float acc0 = 0.0f, acc1 = 0.0f;
    if (kh == 0) {
      #pragma unroll 4
      for (int k = 0; k < 384; k += 2) {
        float x0 = cvT[k * 64 + lane];
        float x1 = cvT[(k + 1) * 64 + lane];
        float2 wa = *(const float2*)(w0 + k);
        float2 wb = *(const float2*)(w1 + k);
        acc0 += x0 * wa.x + x1 * wa.y;
        acc1 += x0 * wb.x + x1 * wb.y;
      }
    } else {
      #pragma unroll 4
      for (int k = 384; k < 512; k += 2) {
        float x0 = cvT[k * 64 + lane];
        float x1 = cvT[(k + 1) * 64 + lane];
        float2 wa = *(const float2*)(w0 + k);
        float2 wb = *(const float2*)(w1 + k);
        acc0 += x0 * wa.x + x1 * wa.y;
        acc1 += x0 * wb.x + x1 * wb.y;
      }
      #pragma unroll 4
      for (int k = 512; k < 768; k += 2) {
        float x0 = poT[(k - 512) * 64 + lane];
        float x1 = poT[(k - 511) * 64 + lane];
        float2 wa = *(const float2*)(w0 + k);
        float2 wb = *(const float2*)(w1 + k);
        acc0 += x0 * wa.x + x1 * wa.y;
        acc1 += x0 * wb.x + x1 * wb.y;
      }
    }
    float* d0 = (n0 < 256) ? (grz + n0 * 64) : (gin + (n0 - 256) * 64);
    float* d1 = (n0 + 1 < 256) ? (grz + (n0 + 1) * 64) : (gin + (n0 + 1 - 256) * 64);
    atomicAdd(d0 + lane, acc0);
    atomicAdd(d1 + lane, acc1);
  } else {
    int n0 = (wv - 384) * 2;
    const float* w0 = gru_w_hh + n0 * 128;
    const float* w1 = w0 + 128;
    float acc0 = 0.0f, acc1 = 0.0f;
    #pragma unroll 4
    for (int k = 0; k < 128; k += 2) {
      float x0 = ahT0[k * 64 + lane];
      float x1 = ahT0[(k + 1) * 64 + lane];
      float2 wa = *(const float2*)(w0 + k);
      float2 wb = *(const float2*)(w1 + k);
      acc0 += x0 * wa.x + x1 * wa.y;
      acc1 += x0 * wb.x + x1 * wb.y;
    }
    float* d0 = (n0 < 256) ? (grz + n0 * 64) : (ghn + (n0 - 256) * 64);
    float* d1 = (n0 + 1 < 256) ? (grz + (n0 + 1) * 64) : (ghn + (n0 + 1 - 256) * 64);
    atomicAdd(d0 + lane, acc0);
    atomicAdd(d1 + lane, acc1);
  }
}

// =================================================================
// Kernel P4: GRU gates (elementwise) -> attn_o + attn_hT
// =================================================================
__global__ __launch_bounds__(256) void kP4(const float* grz, const float* gin, const float* ghn,
                                           const float* ahT0, float* attn_o, float* attn_hT) {
  int i = blockIdx.x * 256 + threadIdx.x;  // 8192
  int j = i >> 6, b = i & 63;
  float r = sigm(grz[i]);
  float z = sigm(grz[8192 + i]);
  float nn = tanh_f(gin[i] + r * ghn[i]);
  float h = (1.0f - z) * nn + z * ahT0[i];
  attn_o[b * 128 + j] = h;
  attn_hT[i] = h;
}

// =================================================================
// Kernel P5: pq_full = attn_h @ W_w.T + W_b + (conv_b @ L_w.T)
// =================================================================
__global__ __launch_bounds__(256) void kP5(const float* attn_hT, const float* W_w, const float* W_b,
                                           const float* conv_b, const float* L_w, float* pq_full) {
  int n = blockIdx.x * 4 + (threadIdx.x >> 6);  // 128 waves
  int lane = threadIdx.x & 63;
  float acc = W_b[n];
  #pragma unroll 8
  for (int f = 0; f < 32; f += 2) {
    float2 lw = *(const float2*)(L_w + n * 32 + f);
    acc += conv_b[f] * lw.x + conv_b[f + 1] * lw.y;
  }
  #pragma unroll 4
  for (int k = 0; k < 128; k += 2) {
    float2 w = *(const float2*)(W_w + n * 128 + k);
    acc += attn_hT[k * 64 + lane] * w.x + attn_hT[(k + 1) * 64 + lane] * w.y;
  }
  pq_full[lane * 128 + n] = acc;
}

// =================================================================
// Kernel B: u[b,t] = sum_d v[d]*tanh(pq[b,d]+esp[b,t,d]) ; mask chars==0
// =================================================================
__global__ __launch_bounds__(256) void kB(const float* esp, const float* v_w, const int* chars,
                                          const float* pq_full, float* u) {
  int wv = blockIdx.x * 4 + (threadIdx.x >> 6);   // 16384 waves
  int lane = threadIdx.x & 63;
  int b = wv >> 8;
  int t0 = (wv & 255) * 4;
  float2 p = *(const float2*)(pq_full + b * 128 + 2 * lane);
  float2 v = *(const float2*)(v_w + 2 * lane);
  const float* erow = esp + ((size_t)b * 1024 + t0) * 128 + 2 * lane;
  float s[4];
  #pragma unroll
  for (int q = 0; q < 4; q++) {
    float2 e = *(const float2*)(erow + q * 128);
    s[q] = v.x * tanh_f(p.x + e.x) + v.y * tanh_f(p.y + e.y);
  }
  #pragma unroll
  for (int q = 0; q < 4; q++)
    for (int off = 32; off > 0; off >>= 1) s[q] += __shfl_down(s[q], off, 64);
  if (lane == 0) {
    #pragma unroll
    for (int q = 0; q < 4; q++) {
      int t = t0 + q;
      u[b * 1024 + t] = (chars[b * 1024 + t] != 0) ? s[q] : 0.0f;
    }
  }
}

// =================================================================
// Kernel C: softmax over T per row; writes scores directly to out (fp32)
// =================================================================
__global__ __launch_bounds__(256) void kC(const float* u, float* scores_o) {
  int b = blockIdx.x, tid = threadIdx.x;
  __shared__ float red[256];
  float4 uv = *(const float4*)(u + b * 1024 + tid * 4);
  float m = fmaxf(fmaxf(uv.x, uv.y), fmaxf(uv.z, uv.w));
  red[tid] = m;
  __syncthreads();
  for (int s = 128; s > 0; s >>= 1) { if (tid < s) red[tid] = fmaxf(red[tid], red[tid + s]); __syncthreads(); }
  float M = red[0];
  __syncthreads();
  float e0 = __expf(uv.x - M), e1 = __expf(uv.y - M), e2 = __expf(uv.z - M), e3 = __expf(uv.w - M);
  red[tid] = e0 + e1 + e2 + e3;
  __syncthreads();
  for (int s = 128; s > 0; s >>= 1) { if (tid < s) red[tid] += red[tid + s]; __syncthreads(); }
  float inv = 1.0f / red[0];
  int o = b * 1024 + tid * 4;
  float4 r; r.x = e0 * inv; r.y = e1 * inv; r.z = e2 * inv; r.w = e3 * inv;
  *(float4*)(scores_o + o) = r;
}

// =================================================================
// Kernel D: context[b,d] += sum_t scores[b,t]*es[b,t,d]  (block = (b, t-chunk of 128))
// =================================================================
__global__ __launch_bounds__(256) void kD(const float* es, const float* scores, float* ctx_f) {
  int b = blockIdx.x >> 3;
  int tc = blockIdx.x & 7;
  int tid = threadIdx.x, g = tid >> 6, lane = tid & 63;
  __shared__ float sc[128];
  __shared__ float red[4][512];
  if (tid < 128) sc[tid] = scores[b * 1024 + tc * 128 + tid];
  __syncthreads();
  float acc[8] = {0, 0, 0, 0, 0, 0, 0, 0};
  const float* base = es + ((size_t)b * 1024 + tc * 128) * 512 + lane * 8;
  for (int i = 0; i < 32; i++) {
    int t = 4 * i + g;
    float4 wa = *(const float4*)(base + (size_t)t * 512);
    float4 wb = *(const float4*)(base + (size_t)t * 512 + 4);
    float s = sc[t];
    acc[0] += s * wa.x; acc[1] += s * wa.y; acc[2] += s * wa.z; acc[3] += s * wa.w;
    acc[4] += s * wb.x; acc[5] += s * wb.y; acc[6] += s * wb.z; acc[7] += s * wb.w;
  }
  #pragma unroll
  for (int j = 0; j < 8; j++) red[g][lane * 8 + j] = acc[j];
  __syncthreads();
  int d0 = tid * 2;
  float r0 = red[0][d0] + red[1][d0] + red[2][d0] + red[3][d0];
  float r1 = red[0][d0 + 1] + red[1][d0 + 1] + red[2][d0 + 1] + red[3][d0 + 1];
  atomicAdd(&ctx_f[b * 512 + d0], r0);
  atomicAdd(&ctx_f[b * 512 + d0 + 1], r1);
}

// =================================================================
// Kernel F: context -> out (fp32) + fp32 transpose
// =================================================================
__global__ __launch_bounds__(256) void kF(const float* ctx_f, float* ctx_o, float* ctxT) {
  int i = blockIdx.x * 256 + threadIdx.x;  // 32768
  int b = i >> 9, d = i & 511;
  float v = ctx_f[i];
  ctx_o[i] = v;
  ctxT[d * 64 + b] = v;
}

// =================================================================
// Kernel E: x = concat(context, attn_h) @ ri_w.T (+ri_b preloaded); atomic into xT
// =================================================================
__global__ __launch_bounds__(256) void kE(const float* ctxT, const float* ahT,
                                          const float* ri_w, float* xT) {
  int wv = blockIdx.x * 4 + (threadIdx.x >> 6);  // 256 waves
  int lane = threadIdx.x & 63;
  int cg = wv & 127, half = wv >> 7;
  int n0 = cg * 4;
  int k0 = half * 320, k1 = k0 + 320;
  float acc[4] = {0, 0, 0, 0};
  for (int k = k0; k < k1; k += 2) {
    float xv0 = (k < 512) ? ctxT[k * 64 + lane] : ahT[(k - 512) * 64 + lane];
    float xv1 = (k + 1 < 512) ? ctxT[(k + 1) * 64 + lane] : ahT[(k + 1 - 512) * 64 + lane];
    #pragma unroll
    for (int j = 0; j < 4; j++) {
      float2 w = *(const float2*)(ri_w + (n0 + j) * 640 + k);
      acc[j] += xv0 * w.x + xv1 * w.y;
    }
  }
  #pragma unroll
  for (int j = 0; j < 4; j++) atomicAdd(&xT[(n0 + j) * 64 + lane], acc[j]);
}

// =================================================================
// Kernel L: LSTM gate matmul: gT[n][b] += x.w_ih (src0) or h.w_hh (src1)
// =================================================================
__global__ __launch_bounds__(256) void kL(const float* XT, const float* HT,
                                          const float* w_ih, const float* w_hh, float* gT) {
  int wv = blockIdx.x * 4 + (threadIdx.x >> 6);  // 512 waves
  int lane = threadIdx.x & 63;
  int src = wv >> 8, cg = wv & 255;
  int n0 = cg * 8;
  const float* S = src ? HT : XT;
  const float* W = src ? w_hh : w_ih;
  float acc[8] = {0, 0, 0, 0, 0, 0, 0, 0};
  for (int k = 0; k < 512; k += 2) {
    float xv0 = S[k * 64 + lane];
    float xv1 = S[k * 64 + 64 + lane];
    #pragma unroll
    for (int j = 0; j < 8; j++) {
      float2 w = *(const float2*)(W + (n0 + j) * 512 + k);
      acc[j] += xv0 * w.x + xv1 * w.y;
    }
  }
  #pragma unroll
  for (int j = 0; j < 8; j++) atomicAdd(&gT[(n0 + j) * 64 + lane], acc[j]);
}

// =================================================================
// Kernel G: LSTM gates + residual; h,c -> out (fp32), xoutT = xinT + h
// =================================================================
__global__ __launch_bounds__(256) void kG(const float* gT, const float* c_in, const float* xinT,
                                          float* h_o, float* c_o, float* xoutT) {
  int i = blockIdx.x * 256 + threadIdx.x;  // 32768
  int b = i & 63, j = i >> 6;
  float gi = gT[j * 64 + b];
  float gf = gT[(512 + j) * 64 + b];
  float gg = gT[(1024 + j) * 64 + b];
  float go = gT[(1536 + j) * 64 + b];
  float c = c_in[b * 512 + j];
  float c2 = sigm(gf) * c + sigm(gi) * tanh_f(gg);
  float h2 = sigm(go) * tanh_f(c2);
  h_o[b * 512 + j] = h2;
  c_o[b * 512 + j] = c2;
  xoutT[j * 64 + b] = xinT[j * 64 + b] + h2;
}

// =================================================================
// Kernel O: mels (80 columns of mp_w, stride MAX_R) + stop projection
// =================================================================
__global__ __launch_bounds__(256) void kO(const float* x3T, const float* ctxT,
                                          const float* mp_w, const float* sp_w, const float* sp_b,
                                          float* mels_o, float* stop_o) {
  int wv = blockIdx.x * 4 + (threadIdx.x >> 6);  // 84 waves
  int lane = threadIdx.x & 63;
  if (wv < 80) {
    int m = wv;
    const float* wr = mp_w + (size_t)m * 20 * 512;
    float acc = 0.0f;
    for (int k = 0; k < 512; k += 2) {
      float2 w = *(const float2*)(wr + k);
      acc += x3T[k * 64 + lane] * w.x + x3T[(k + 1) * 64 + lane] * w.y;
    }
    mels_o[lane * 80 + m] = acc;
  } else if (wv == 80) {
    float acc = sp_b[0];
    for (int k = 0; k < 512; k += 2) {
      float2 w = *(const float2*)(sp_w + k);
      acc += x3T[k * 64 + lane] * w.x + x3T[(k + 1) * 64 + lane] * w.y;
    }
    for (int k = 0; k < 512; k += 2) {
      float2 w = *(const float2*)(sp_w + 512 + k);
      acc += ctxT[k * 64 + lane] * w.x + ctxT[(k + 1) * 64 + lane] * w.y;
    }
    stop_o[lane] = sigm(acc);
  }
}

// =================================================================
extern "C" void kernel_launch(void* const* d_in, const int* in_sizes, int n_in,
                              void* d_out, int out_size, void* d_ws, size_t ws_size,
                              hipStream_t stream) {
  const float* es          = (const float*)d_in[0];
  const float* esp         = (const float*)d_in[1];
  const float* prenet_in   = (const float*)d_in[2];
  const float* attn_hidden = (const float*)d_in[3];
  const float* rnn1_hidden = (const float*)d_in[4];
  const float* rnn2_hidden = (const float*)d_in[5];
  const float* rnn1_cell   = (const float*)d_in[6];
  const float* rnn2_cell   = (const float*)d_in[7];
  const float* context_vec = (const float*)d_in[8];
  const int* chars         = (const int*)d_in[9];
  // d_in[10] = t (unused), d_in[11] = conv_w (unused: conv input is zeros)
  const float* conv_b = (const float*)d_in[12];
  const float* L_w    = (const float*)d_in[13];
  const float* W_w    = (const float*)d_in[14];
  const float* W_b    = (const float*)d_in[15];
  const float* v_w    = (const float*)d_in[16];
  const float* fc1_w  = (const float*)d_in[17];
  const float* fc1_b  = (const float*)d_in[18];
  const float* fc2_w  = (const float*)d_in[19];
  const float* fc2_b  = (const float*)d_in[20];
  const float* gru_w_ih = (const float*)d_in[21];
  const float* gru_w_hh = (const float*)d_in[22];
  const float* gru_b_ih = (const float*)d_in[23];
  const float* gru_b_hh = (const float*)d_in[24];
  const float* ri_w   = (const float*)d_in[25];
  const float* ri_b   = (const float*)d_in[26];
  const float* l1_w_ih = (const float*)d_in[27];
  const float* l1_w_hh = (const float*)d_in[28];
  const float* l1_b_ih = (const float*)d_in[29];
  const float* l1_b_hh = (const float*)d_in[30];
  const float* l2_w_ih = (const float*)d_in[31];
  const float* l2_w_hh = (const float*)d_in[32];
  const float* l2_b_ih = (const float*)d_in[33];
  const float* l2_b_hh = (const float*)d_in[34];
  const float* mp_w = (const float*)d_in[35];
  const float* sp_w = (const float*)d_in[36];
  const float* sp_b = (const float*)d_in[37];

  float* out = (float*)d_out;
  float* ws = (float*)d_ws;
  float* attn_hT  = ws;             // 8192
  float* pq_full  = ws + 8192;      // 8192
  float* u_buf    = ws + 16384;     // 65536
  float* ctx_f    = ws + 81920;     // 32768
  float* ctxT     = ws + 114688;    // 32768
  float* xT       = ws + 147456;    // 32768
  float* x2T      = ws + 180224;    // 32768
  float* x3T      = ws + 212992;    // 32768
  float* g1T      = ws + 245760;    // 131072
  float* g2T      = ws + 376832;    // 131072
  float* h1pT     = ws + 507904;    // 32768
  float* h2pT     = ws + 540672;    // 32768
  float* pinT     = ws + 573440;    // 5120
  float* cvT      = ws + 578560;    // 32768
  float* ahT0     = ws + 611328;    // 8192
  float* phT      = ws + 619520;    // 16384
  float* poT      = ws + 635904;    // 16384
  float* grz      = ws + 652288;    // 16384
  float* gin      = ws + 668672;    // 8192
  float* ghn      = ws + 676864;    // 8192 (end 685056 floats = 2.74 MB)

  float* mels_o   = out + 0;
  float* scores_o = out + 5120;
  float* attn_o   = out + 70656;
  float* h1_o     = out + 78848;
  float* h2_o     = out + 111616;
  float* c1_o     = out + 144384;
  float* c2_o     = out + 177152;
  float* ctx_o    = out + 209920;
  float* stop_o   = out + 242688;

  kP0<<<128, 256, 0, stream>>>(prenet_in, context_vec, attn_hidden, rnn1_hidden, rnn2_hidden,
                               ri_b, l1_b_ih, l1_b_hh, l2_b_ih, l2_b_hh, gru_b_ih, gru_b_hh,
                               ctx_f, xT, g1T, g2T, h1pT, h2pT,
                               pinT, cvT, ahT0, grz, gin, ghn);
  kP1<<<16, 256, 0, stream>>>(pinT, fc1_w, fc1_b, phT);
  kP2<<<16, 256, 0, stream>>>(phT, fc2_w, fc2_b, poT);
  kP3<<<144, 256, 0, stream>>>(cvT, poT, ahT0, gru_w_ih, gru_w_hh, grz, gin, ghn);
  kP4<<<32, 256, 0, stream>>>(grz, gin, ghn, ahT0, attn_o, attn_hT);
  kP5<<<32, 256, 0, stream>>>(attn_hT, W_w, W_b, conv_b, L_w, pq_full);
  kB<<<4096, 256, 0, stream>>>(esp, v_w, chars, pq_full, u_buf);
  kC<<<64, 256, 0, stream>>>(u_buf, scores_o);
  kD<<<512, 256, 0, stream>>>(es, scores_o, ctx_f);
  kF<<<128, 256, 0, stream>>>(ctx_f, ctx_o, ctxT);
  kE<<<64, 256, 0, stream>>>(ctxT, attn_hT, ri_w, xT);
  kL<<<128, 256, 0, stream>>>(xT, h1pT, l1_w_ih, l1_w_hh, g1T);
  kG<<<128, 256, 0, stream>>>(g1T, rnn1_cell, xT, h1_o, c1_o, x2T);
  kL<<<128, 256, 0, stream>>>(x2T, h2pT, l2_w_ih, l2_w_hh, g2T);
  kG<<<128, 256, 0, stream>>>(g2T, rnn2_cell, x2T, h2_o, c2_o, x3T);
  kO<<<21, 256, 0, stream>>>(x3T, ctxT, mp_w, sp_w, sp_b, mels_o, stop_o);
}